// Round 17
// baseline (265.204 us; speedup 1.0000x reference)
//
#include <hip/hip_runtime.h>

typedef __attribute__((ext_vector_type(8))) short bf16x8;
typedef __attribute__((ext_vector_type(4))) float f32x4;

__device__ __forceinline__ unsigned short f2bf(float f) {
  unsigned int u = __builtin_bit_cast(unsigned int, f);
  u += 0x7fffu + ((u >> 16) & 1u);   // RNE
  return (unsigned short)(u >> 16);
}

#define GLD16(gp, lp) __builtin_amdgcn_global_load_lds( \
    (const __attribute__((address_space(1))) unsigned int*)(gp), \
    (__attribute__((address_space(3))) unsigned int*)(lp), 16, 0, 0)

// ---------------------------------------------------------------------------
// Self-detecting mask pack (r11-verified): pm[g] bit b = (mask[g*64+b] != 0).
__global__ __launch_bounds__(256) void pack_mask(
    const unsigned char* __restrict__ m, unsigned long long* __restrict__ pm)
{
  __shared__ int mode1;
  if (threadIdx.x == 0) mode1 = 0;
  __syncthreads();

  const int g = blockIdx.x * 256 + threadIdx.x;  // 0..524287
  const size_t base = (size_t)g * 64;

  uint4 v[4];
  const uint4* p1 = (const uint4*)(m + base);
  v[0] = p1[0]; v[1] = p1[1]; v[2] = p1[2]; v[3] = p1[3];
  unsigned int probe = 0;
#pragma unroll
  for (int j = 0; j < 4; ++j)
    probe |= (v[j].x | v[j].y | v[j].z | v[j].w);
  if (probe & 0x0000ff00u) mode1 = 1;   // benign race
  __syncthreads();

  unsigned long long bits = 0;
  if (mode1) {
#pragma unroll
    for (int j = 0; j < 4; ++j) {
      unsigned int w[4] = {v[j].x, v[j].y, v[j].z, v[j].w};
#pragma unroll
      for (int q = 0; q < 4; ++q) {
        unsigned int u = w[q];
#pragma unroll
        for (int b = 0; b < 4; ++b)
          if ((u >> (8 * b)) & 0xffu) bits |= 1ull << (j * 16 + q * 4 + b);
      }
    }
  } else {
    const uint4* p4 = (const uint4*)(m + base * 4);
#pragma unroll
    for (int j = 0; j < 16; ++j) {
      uint4 w = p4[j];
      if (w.x) bits |= 1ull << (j * 4 + 0);
      if (w.y) bits |= 1ull << (j * 4 + 1);
      if (w.z) bits |= 1ull << (j * 4 + 2);
      if (w.w) bits |= 1ull << (j * 4 + 3);
    }
  }
  pm[g] = bits;
}

// ---------------------------------------------------------------------------
// Prep: activation converts + weight bf16 copies (wq, wk plain; wv transposed).
__global__ void prep(const float* __restrict__ query, const float* __restrict__ node,
                     const float* __restrict__ wq, const float* __restrict__ wk,
                     const float* __restrict__ wv,
                     unsigned short* __restrict__ Xq, unsigned short* __restrict__ Xn,
                     unsigned short* __restrict__ wqb, unsigned short* __restrict__ wkb,
                     unsigned short* __restrict__ wvt)
{
  const int b = blockIdx.x;
  if (b < 16384) {
    int i = b * 256 + threadIdx.x;
    const float* src;
    unsigned short* dst;
    int j;
    if (i < 2097152) { src = query; dst = Xq; j = i; }
    else             { src = node;  dst = Xn; j = i - 2097152; }
    float4 v = ((const float4*)src)[j];
    ushort4 o;
    o.x = f2bf(v.x); o.y = f2bf(v.y); o.z = f2bf(v.z); o.w = f2bf(v.w);
    ((ushort4*)dst)[j] = o;
  } else {
    int idx = (b - 16384) * 256 + threadIdx.x;  // 0..786431
    int w = idx >> 18;
    int rem = idx & 262143;
    if (w == 0)      wqb[rem] = f2bf(wq[rem]);
    else if (w == 1) wkb[rem] = f2bf(wk[rem]);
    else {
      int n = rem >> 9, k = rem & 511;
      wvt[n * 512 + k] = f2bf(wv[k * 512 + n]);
    }
  }
}

// ---------------------------------------------------------------------------
// Unified 128x128 core (r12/r14-verified), bf16 output.
__device__ __forceinline__ void core128(
    const unsigned short* __restrict__ Ab, const unsigned short* __restrict__ Bb,
    void* __restrict__ Cb, long ldA, long ldB, long ldO, int nk,
    long bm, long bn, char* smem)
{
  const int tid = threadIdx.x;
  const int lane = tid & 63;
  const int wid = tid >> 6;
  const int wr = wid >> 1, wc = wid & 1;
  const int fr = lane & 15, fq = lane >> 4;

  const int srow = tid >> 2;
  const int sch = (tid & 3) ^ ((srow >> 1) & 3);

  char* bufs[3] = { smem, smem + 16384, smem + 32768 };

#define STAGE_C(buf, kt) do { \
    const long k0_ = (long)(kt) << 5; \
    GLD16(Ab + (bm + srow) * ldA + k0_ + sch * 8,        (buf) + tid * 16); \
    GLD16(Ab + (bm + 64 + srow) * ldA + k0_ + sch * 8,   (buf) + 4096 + tid * 16); \
    GLD16(Bb + (bn + srow) * ldB + k0_ + sch * 8,        (buf) + 8192 + tid * 16); \
    GLD16(Bb + (bn + 64 + srow) * ldB + k0_ + sch * 8,   (buf) + 12288 + tid * 16); \
  } while (0)

  int aoff[4], boff[4];
#pragma unroll
  for (int i = 0; i < 4; ++i) {
    const int ra = wr * 64 + i * 16 + fr;
    aoff[i] = ra * 64 + (fq ^ ((ra >> 1) & 3)) * 16;
    const int rb = wc * 64 + i * 16 + fr;
    boff[i] = 8192 + rb * 64 + (fq ^ ((rb >> 1) & 3)) * 16;
  }

  f32x4 acc[4][4] = {};

  STAGE_C(bufs[0], 0);
  STAGE_C(bufs[1], 1);
  char* c0 = bufs[0]; char* c1 = bufs[1]; char* c2 = bufs[2];

  for (int t = 0; t < nk; ++t) {
    __builtin_amdgcn_sched_barrier(0);
    __builtin_amdgcn_s_barrier();
    if (t + 2 < nk) {
      STAGE_C(c2, t + 2);
      asm volatile("s_waitcnt vmcnt(8)" ::: "memory");
    } else if (t + 2 == nk) {
      asm volatile("s_waitcnt vmcnt(4)" ::: "memory");
    } else {
      asm volatile("s_waitcnt vmcnt(0)" ::: "memory");
    }
    __builtin_amdgcn_s_barrier();
    __builtin_amdgcn_sched_barrier(0);

    bf16x8 a[4];
#pragma unroll
    for (int mi = 0; mi < 4; ++mi)
      a[mi] = *(const bf16x8*)(c0 + aoff[mi]);
    __builtin_amdgcn_s_setprio(1);
#pragma unroll
    for (int nj = 0; nj < 4; ++nj) {
      const bf16x8 b = *(const bf16x8*)(c0 + boff[nj]);
#pragma unroll
      for (int mi = 0; mi < 4; ++mi)
        acc[mi][nj] = __builtin_amdgcn_mfma_f32_16x16x32_bf16(a[mi], b, acc[mi][nj], 0, 0, 0);
    }
    __builtin_amdgcn_s_setprio(0);

    char* tmp = c0; c0 = c1; c1 = c2; c2 = tmp;
  }
#undef STAGE_C

  unsigned short* C = (unsigned short*)Cb;
#pragma unroll
  for (int mi = 0; mi < 4; ++mi)
#pragma unroll
    for (int nj = 0; nj < 4; ++nj) {
      const long row = bm + wr * 64 + mi * 16 + fq * 4;
      const long col = bn + wc * 64 + nj * 16 + fr;
#pragma unroll
      for (int r = 0; r < 4; ++r)
        C[(row + r) * ldO + col] = f2bf(acc[mi][nj][r]);
    }
}

// MT = Wk_bf * Wq_bf^T. grid(4,4,1).
__global__ __launch_bounds__(256, 3) void gemm_mt(
    const unsigned short* __restrict__ wkb, const unsigned short* __restrict__ wqb,
    unsigned short* __restrict__ MT)
{
  extern __shared__ char smem[];
  core128(wkb, wqb, MT, 512, 512, 512, 16,
          (long)blockIdx.x * 128, (long)blockIdx.y * 128, smem);
}

// Projections, grid(128,4,2): z=0: T = Xq*MT^T; z=1: Vt = Wvt*Xn^T [512x16384]
__global__ __launch_bounds__(256, 3) void gemm_proj(
    const unsigned short* __restrict__ Xq, const unsigned short* __restrict__ Xn,
    const unsigned short* __restrict__ MT, const unsigned short* __restrict__ Wvt,
    unsigned short* __restrict__ T, unsigned short* __restrict__ Vt)
{
  extern __shared__ char smem[];
  if (blockIdx.z == 0) {
    core128(Xq, MT, T, 512, 512, 512, 16,
            (long)blockIdx.x * 128, (long)blockIdx.y * 128, smem);
  } else {
    core128(Wvt, Xn, Vt, 512, 512, 16384, 16,
            (long)blockIdx.y * 128, (long)blockIdx.x * 128, smem);
  }
}

// ---------------------------------------------------------------------------
// Fused flash-style attention: per block 64 q-rows x full d=512, one batch.
// Iterates 64 kv-tiles of 32. QK^T (T-frags in regs, Xn staged) -> exp+mask
// -> P[64x32] bf16 in LDS + LDS rowsum atomics -> PV (Vt staged) into f32 acc.
// E is never materialized. grid(8 batch=XCD, 32 q-panels) = 256 blocks.
// LDS: XB0/XB1 32KB @0/32768 | VB0/VB1 32KB @65536/98304 | P 4KB @131072
//      | sums 256B @135168. Total 135424.
__global__ __launch_bounds__(512, 1) void fused_attn(
    const unsigned short* __restrict__ Tg, const unsigned short* __restrict__ Xng,
    const unsigned short* __restrict__ Vtg, const unsigned long long* __restrict__ pm,
    float* __restrict__ Og)
{
  extern __shared__ char smem[];
  const long z  = blockIdx.x;                 // batch = XCD
  const long q0 = (long)blockIdx.y * 64;

  const unsigned short* Tb  = Tg  + z * 1048576;
  const unsigned short* Xnb = Xng + z * 1048576;
  const unsigned short* Vtb = Vtg + z * 2048;        // ld 16384
  const unsigned long long* pmz = pm + z * 65536;
  float* Ob = Og + z * 1048576;

  const int tid = threadIdx.x;
  const int lane = tid & 63;
  const int w = tid >> 6;                     // 0..7
  const int fr = lane & 15, fq = lane >> 4;
  const int qf = w >> 1;                      // QK: q-frag 0..3
  const int kf = w & 1;                      // QK: kv half 0..1

  // Scalar pointer assignments only (aggregate init from extern __shared__
  // triggers the addrspacecast-static-initializer compile error).
  char* XB0 = smem;
  char* XB1 = smem + 32768;
  char* VB0 = smem + 65536;
  char* VB1 = smem + 98304;
  char* PB = smem + 131072;
  float* sums_l = (float*)(smem + 135168);

  if (tid < 64) sums_l[tid] = 0.0f;

  // Preload T fragments (held in registers for all 64 iterations)
  bf16x8 af[16];
  {
    const unsigned short* tp = Tb + (q0 + qf * 16 + fr) * 512 + fq * 8;
#pragma unroll
    for (int s = 0; s < 16; ++s)
      af[s] = *(const bf16x8*)(tp + s * 32);
  }

  // Staging geometry
  const int xr = tid >> 6;                    // Xn: wave-uniform row-in-pass 0..7
  const int xcs = (tid & 63) ^ (xr & 7);      // pre-swizzled source chunk
  const int vr = tid >> 2;                    // V: row-in-pass 0..127
  const int vcs = (tid & 3) ^ ((vr >> 1) & 3);

#define STAGE_F(xb_, vb_, kv0_) do { \
    const unsigned short* xs_ = Xnb + ((kv0_) + xr) * 512 + xcs * 8; \
    GLD16(xs_,              (xb_) + tid * 16); \
    GLD16(xs_ + 8 * 512,    (xb_) + 8192 + tid * 16); \
    GLD16(xs_ + 16 * 512,   (xb_) + 16384 + tid * 16); \
    GLD16(xs_ + 24 * 512,   (xb_) + 24576 + tid * 16); \
    const unsigned short* vs_ = Vtb + (long)vr * 16384 + (kv0_) + vcs * 8; \
    GLD16(vs_,                   (vb_) + tid * 16); \
    GLD16(vs_ + 128L * 16384,    (vb_) + 8192 + tid * 16); \
    GLD16(vs_ + 256L * 16384,    (vb_) + 16384 + tid * 16); \
    GLD16(vs_ + 384L * 16384,    (vb_) + 24576 + tid * 16); \
  } while (0)

  const int kvl = kf * 16 + fr;               // QK: this lane's kv col (0..31)
  const int ksw = kvl & 7;

  f32x4 acc[4][4] = {};                       // PV acc: 64q x 64d (wave's d-slice)
  const float SCALE = 0.04419417382415922f;   // 1/sqrt(512)

  STAGE_F(XB0, VB0, 0);

  for (int it = 0; it < 64; ++it) {
    const int kv0 = it * 32;
    char* xb = (it & 1) ? XB1 : XB0;
    char* vb = (it & 1) ? VB1 : VB0;
    char* xbn = (it & 1) ? XB0 : XB1;
    char* vbn = (it & 1) ? VB0 : VB1;

    __builtin_amdgcn_sched_barrier(0);
    __builtin_amdgcn_s_barrier();             // B1: next buffer free
    if (it + 1 < 64) {
      STAGE_F(xbn, vbn, kv0 + 32);
      asm volatile("s_waitcnt vmcnt(8)" ::: "memory");   // tile it landed
    } else {
      asm volatile("s_waitcnt vmcnt(0)" ::: "memory");
    }
    __builtin_amdgcn_s_barrier();             // B2: tile it visible
    __builtin_amdgcn_sched_barrier(0);

    // ---- QK^T: one 16x16 S-frag per wave (q rows qf*16.., kv cols kf*16..)
    f32x4 sacc = {};
    __builtin_amdgcn_s_setprio(1);
#pragma unroll
    for (int s = 0; s < 16; ++s) {
      const bf16x8 b = *(const bf16x8*)(xb + kvl * 1024 + (((s * 4 + fq) ^ ksw) * 16));
      sacc = __builtin_amdgcn_mfma_f32_16x16x32_bf16(af[s], b, sacc, 0, 0, 0);
    }
    __builtin_amdgcn_s_setprio(0);

    // ---- exp + mask -> P (bf16, swizzled LDS) + rowsum partials
    const int wordc = (kv0 + kf * 16) >> 6;
#pragma unroll
    for (int i = 0; i < 4; ++i) {
      const int prow = qf * 16 + fq * 4 + i;
      const unsigned long long mw = pmz[(q0 + prow) * 32 + wordc];
      const int bit = (kv0 + kvl) & 63;
      float e = ((mw >> bit) & 1ull) ? 0.0f : __expf(sacc[i] * SCALE);
      const int pchunk = (kf * 2 + (fr >> 3)) ^ ((prow >> 1) & 3);
      *(unsigned short*)(PB + prow * 64 + pchunk * 16 + (fr & 7) * 2) = f2bf(e);
      float s_ = e;
      s_ += __shfl_xor(s_, 1); s_ += __shfl_xor(s_, 2);
      s_ += __shfl_xor(s_, 4); s_ += __shfl_xor(s_, 8);
      if (fr == 0) atomicAdd(&sums_l[prow], s_);
    }

    asm volatile("s_waitcnt lgkmcnt(0)" ::: "memory");
    __builtin_amdgcn_sched_barrier(0);
    __builtin_amdgcn_s_barrier();             // B3: P complete
    __builtin_amdgcn_sched_barrier(0);

    // ---- PV: wave's 64q x 64d slice, K = 32 (one MFMA per frag)
    bf16x8 pa[4];
#pragma unroll
    for (int m = 0; m < 4; ++m) {
      const int prow = m * 16 + fr;
      pa[m] = *(const bf16x8*)(PB + prow * 64 + ((fq ^ ((prow >> 1) & 3)) * 16));
    }
    __builtin_amdgcn_s_setprio(1);
#pragma unroll
    for (int n = 0; n < 4; ++n) {
      const int vrow = w * 64 + n * 16 + fr;
      const bf16x8 bv = *(const bf16x8*)(vb + vrow * 64 + ((fq ^ ((vrow >> 1) & 3)) * 16));
#pragma unroll
      for (int m = 0; m < 4; ++m)
        acc[m][n] = __builtin_amdgcn_mfma_f32_16x16x32_bf16(pa[m], bv, acc[m][n], 0, 0, 0);
    }
    __builtin_amdgcn_s_setprio(0);
  }
#undef STAGE_F

  // Final: normalize by row sums and write out (f32, coalesced per 16 lanes)
  asm volatile("s_waitcnt lgkmcnt(0)" ::: "memory");
  __builtin_amdgcn_sched_barrier(0);
  __builtin_amdgcn_s_barrier();               // all rowsum atomics done
#pragma unroll
  for (int m = 0; m < 4; ++m)
#pragma unroll
    for (int r = 0; r < 4; ++r) {
      const int qr = m * 16 + fq * 4 + r;
      const float iv = 1.0f / sums_l[qr];
      float* orow = Ob + (q0 + qr) * 512 + w * 64 + fr;
#pragma unroll
      for (int n = 0; n < 4; ++n)
        orow[n * 16] = acc[m][n][r] * iv;
    }
}

// ---------------------------------------------------------------------------
extern "C" void kernel_launch(void* const* d_in, const int* in_sizes, int n_in,
                              void* d_out, int out_size, void* d_ws, size_t ws_size,
                              hipStream_t stream) {
  const float* node  = (const float*)d_in[0];
  const float* query = (const float*)d_in[1];
  const unsigned char* mask = (const unsigned char*)d_in[2];
  const float* wq = (const float*)d_in[3];
  const float* wk = (const float*)d_in[4];
  const float* wv = (const float*)d_in[5];
  float* out = (float*)d_out;

  char* ws = (char*)d_ws;
  // ws: T @0 (16M) | Xn @16M (16M) | Vt @32M (16M) | Xq @48M (16M, dead after T)
  //     wqb/wkb/Wvt/MT @64M+ (dead after proj) | pm @~113M (4M)
  unsigned short* T   = (unsigned short*)(ws);
  unsigned short* Xn  = (unsigned short*)(ws + 16777216);
  unsigned short* Vt  = (unsigned short*)(ws + 33554432);
  unsigned short* Xq  = (unsigned short*)(ws + 50331648);
  unsigned short* wqb = (unsigned short*)(ws + 67108864);
  unsigned short* wkb = (unsigned short*)(ws + 67633152);
  unsigned short* Wvt = (unsigned short*)(ws + 68157440);
  unsigned short* MT  = (unsigned short*)(ws + 68681728);
  unsigned long long* pm = (unsigned long long*)(ws + 118489088);

  pack_mask<<<2048, 256, 0, stream>>>(mask, pm);
  prep<<<19456, 256, 0, stream>>>(query, node, wq, wk, wv,
                                  Xq, Xn, wqb, wkb, Wvt);

  // MT = Wk*Wq^T (512x512)
  gemm_mt<<<dim3(4, 4, 1), 256, 49152, stream>>>(wkb, wqb, MT);

  // T = Xq*MT^T and Vt = Wvt*Xn^T
  dim3 gp(128, 4, 2);
  gemm_proj<<<gp, 256, 49152, stream>>>(Xq, Xn, MT, Wvt, T, Vt);

  // Fused scores+softmax+PV (E never materialized)
  dim3 gf(8, 32, 1);
  fused_attn<<<gf, 512, 135424, stream>>>(T, Xn, Vt, pm, out);
}

// Round 18
// 196.340 us; speedup vs baseline: 1.3507x; 1.3507x over previous
//
#include <hip/hip_runtime.h>

typedef __attribute__((ext_vector_type(8))) short bf16x8;
typedef __attribute__((ext_vector_type(4))) float f32x4;

__device__ __forceinline__ unsigned short f2bf(float f) {
  unsigned int u = __builtin_bit_cast(unsigned int, f);
  u += 0x7fffu + ((u >> 16) & 1u);   // RNE
  return (unsigned short)(u >> 16);
}

#define GLD16(gp, lp) __builtin_amdgcn_global_load_lds( \
    (const __attribute__((address_space(1))) unsigned int*)(gp), \
    (__attribute__((address_space(3))) unsigned int*)(lp), 16, 0, 0)

// ---------------------------------------------------------------------------
// Merged prep: [0,2048) mask pack (self-detecting); [2048,18432) activation
// converts; [18432,21504-... ) weight copies; tail sums zeroing.
__global__ __launch_bounds__(256) void prep_all(
    const unsigned char* __restrict__ m, unsigned long long* __restrict__ pm,
    const float* __restrict__ query, const float* __restrict__ node,
    const float* __restrict__ wq, const float* __restrict__ wk,
    const float* __restrict__ wv,
    unsigned short* __restrict__ Xq, unsigned short* __restrict__ Xn,
    unsigned short* __restrict__ wqb, unsigned short* __restrict__ wkb,
    unsigned short* __restrict__ wvt, float* __restrict__ sums)
{
  const int b = blockIdx.x;
  if (b < 2048) {
    // ---- mask pack (r11-verified logic) ----
    __shared__ int mode1;
    if (threadIdx.x == 0) mode1 = 0;
    __syncthreads();

    const int g = b * 256 + threadIdx.x;  // 0..524287
    const size_t base = (size_t)g * 64;

    uint4 v[4];
    const uint4* p1 = (const uint4*)(m + base);
    v[0] = p1[0]; v[1] = p1[1]; v[2] = p1[2]; v[3] = p1[3];
    unsigned int probe = 0;
#pragma unroll
    for (int j = 0; j < 4; ++j)
      probe |= (v[j].x | v[j].y | v[j].z | v[j].w);
    if (probe & 0x0000ff00u) mode1 = 1;   // benign race
    __syncthreads();

    unsigned long long bits = 0;
    if (mode1) {
#pragma unroll
      for (int j = 0; j < 4; ++j) {
        unsigned int w[4] = {v[j].x, v[j].y, v[j].z, v[j].w};
#pragma unroll
        for (int q = 0; q < 4; ++q) {
          unsigned int u = w[q];
#pragma unroll
          for (int bb = 0; bb < 4; ++bb)
            if ((u >> (8 * bb)) & 0xffu) bits |= 1ull << (j * 16 + q * 4 + bb);
        }
      }
    } else {
      const uint4* p4 = (const uint4*)(m + base * 4);
#pragma unroll
      for (int j = 0; j < 16; ++j) {
        uint4 w = p4[j];
        if (w.x) bits |= 1ull << (j * 4 + 0);
        if (w.y) bits |= 1ull << (j * 4 + 1);
        if (w.z) bits |= 1ull << (j * 4 + 2);
        if (w.w) bits |= 1ull << (j * 4 + 3);
      }
    }
    pm[g] = bits;
  } else if (b < 18432) {
    int i = (b - 2048) * 256 + threadIdx.x;
    const float* src;
    unsigned short* dst;
    int j;
    if (i < 2097152) { src = query; dst = Xq; j = i; }
    else             { src = node;  dst = Xn; j = i - 2097152; }
    float4 v = ((const float4*)src)[j];
    ushort4 o;
    o.x = f2bf(v.x); o.y = f2bf(v.y); o.z = f2bf(v.z); o.w = f2bf(v.w);
    ((ushort4*)dst)[j] = o;
  } else if (b < 21504) {
    int idx = (b - 18432) * 256 + threadIdx.x;  // 0..786431
    int w = idx >> 18;
    int rem = idx & 262143;
    if (w == 0)      wqb[rem] = f2bf(wq[rem]);
    else if (w == 1) wkb[rem] = f2bf(wk[rem]);
    else {
      int n = rem >> 9, k = rem & 511;
      wvt[n * 512 + k] = f2bf(wv[k * 512 + n]);
    }
  } else {
    int idx = (b - 21504) * 256 + threadIdx.x;  // 0..16383
    sums[idx] = 0.0f;
  }
}

// ---------------------------------------------------------------------------
// Unified 128x128 core, 3 blocks/CU (r12/r14/r15-verified): BK=32, 4 waves,
// 3 bufs x 16KB = 48KB LDS. Stage t+2 during t; vmcnt ledger 8/4/0 (L=4).
// Swizzle: 16B-chunk ^= ((row>>1)&3) -> 2-way max (conflict-count 0, r14).
// mode 0: bf16 C. mode 1: scores epilogue (bitmask exp + rowsum atomics).
// mode 2: f32 C scaled by 1/sums[row].
__device__ __forceinline__ void core128(
    const unsigned short* __restrict__ Ab, const unsigned short* __restrict__ Bb,
    void* __restrict__ Cb, long ldA, long ldB, long ldO, int nk,
    long bm, long bn, char* smem, int mode,
    const unsigned long long* __restrict__ pmask, float* __restrict__ sumz,
    const float* __restrict__ sums_ro)
{
  const int tid = threadIdx.x;          // 0..255
  const int lane = tid & 63;
  const int wid = tid >> 6;
  const int wr = wid >> 1, wc = wid & 1;
  const int fr = lane & 15, fq = lane >> 4;

  const int srow = tid >> 2;            // 0..63
  const int sch = (tid & 3) ^ ((srow >> 1) & 3);   // pre-swizzled source chunk

  char* bufs[3] = { smem, smem + 16384, smem + 32768 };

#define STAGE_C(buf, kt) do { \
    const long k0_ = (long)(kt) << 5; \
    GLD16(Ab + (bm + srow) * ldA + k0_ + sch * 8,        (buf) + tid * 16); \
    GLD16(Ab + (bm + 64 + srow) * ldA + k0_ + sch * 8,   (buf) + 4096 + tid * 16); \
    GLD16(Bb + (bn + srow) * ldB + k0_ + sch * 8,        (buf) + 8192 + tid * 16); \
    GLD16(Bb + (bn + 64 + srow) * ldB + k0_ + sch * 8,   (buf) + 12288 + tid * 16); \
  } while (0)

  int aoff[4], boff[4];
#pragma unroll
  for (int i = 0; i < 4; ++i) {
    const int ra = wr * 64 + i * 16 + fr;
    aoff[i] = ra * 64 + (fq ^ ((ra >> 1) & 3)) * 16;
    const int rb = wc * 64 + i * 16 + fr;
    boff[i] = 8192 + rb * 64 + (fq ^ ((rb >> 1) & 3)) * 16;
  }

  f32x4 acc[4][4] = {};

  STAGE_C(bufs[0], 0);
  STAGE_C(bufs[1], 1);
  char* c0 = bufs[0]; char* c1 = bufs[1]; char* c2 = bufs[2];

  for (int t = 0; t < nk; ++t) {
    __builtin_amdgcn_sched_barrier(0);
    __builtin_amdgcn_s_barrier();       // B1: all reads of c2's old tile done
    if (t + 2 < nk) {
      STAGE_C(c2, t + 2);
      asm volatile("s_waitcnt vmcnt(8)" ::: "memory");   // tile t landed
    } else if (t + 2 == nk) {
      asm volatile("s_waitcnt vmcnt(4)" ::: "memory");
    } else {
      asm volatile("s_waitcnt vmcnt(0)" ::: "memory");
    }
    __builtin_amdgcn_s_barrier();       // B2: tile t visible to all waves
    __builtin_amdgcn_sched_barrier(0);

    bf16x8 a[4];
#pragma unroll
    for (int mi = 0; mi < 4; ++mi)
      a[mi] = *(const bf16x8*)(c0 + aoff[mi]);
    __builtin_amdgcn_s_setprio(1);
#pragma unroll
    for (int nj = 0; nj < 4; ++nj) {
      const bf16x8 b = *(const bf16x8*)(c0 + boff[nj]);
#pragma unroll
      for (int mi = 0; mi < 4; ++mi)
        acc[mi][nj] = __builtin_amdgcn_mfma_f32_16x16x32_bf16(a[mi], b, acc[mi][nj], 0, 0, 0);
    }
    __builtin_amdgcn_s_setprio(0);

    char* tmp = c0; c0 = c1; c1 = c2; c2 = tmp;
  }
#undef STAGE_C

  // Epilogue. C/D layout: col=lane&15, row=(lane>>4)*4+r  [m89-verified]
  const float SCALE = 0.04419417382415922f;  // 1/sqrt(512)
  if (mode == 0) {
    unsigned short* C = (unsigned short*)Cb;
#pragma unroll
    for (int mi = 0; mi < 4; ++mi)
#pragma unroll
      for (int nj = 0; nj < 4; ++nj) {
        const long row = bm + wr * 64 + mi * 16 + fq * 4;
        const long col = bn + wc * 64 + nj * 16 + fr;
#pragma unroll
        for (int r = 0; r < 4; ++r)
          C[(row + r) * ldO + col] = f2bf(acc[mi][nj][r]);
      }
  } else if (mode == 1) {
    unsigned short* C = (unsigned short*)Cb;
    const long wword = (bn >> 6) + wc;
#pragma unroll
    for (int mi = 0; mi < 4; ++mi) {
      const long rowb = bm + wr * 64 + mi * 16 + fq * 4;
#pragma unroll
      for (int r = 0; r < 4; ++r) {
        const long row = rowb + r;
        const unsigned long long w = pmask[row * 32 + wword];
        unsigned short* Crow = C + row * ldO + bn + wc * 64 + fr;
        float s = 0.f;
#pragma unroll
        for (int nj = 0; nj < 4; ++nj) {
          const int sh = nj * 16 + fr;
          float e = ((w >> sh) & 1ull) ? 0.0f : __expf(acc[mi][nj][r] * SCALE);
          s += e;
          Crow[nj * 16] = f2bf(e);
        }
        s += __shfl_xor(s, 1); s += __shfl_xor(s, 2);
        s += __shfl_xor(s, 4); s += __shfl_xor(s, 8);
        if (fr == 0) atomicAdd(&sumz[row], s);
      }
    }
  } else {
    float* C = (float*)Cb;
#pragma unroll
    for (int mi = 0; mi < 4; ++mi) {
      const long rowb = bm + wr * 64 + mi * 16 + fq * 4;
#pragma unroll
      for (int r = 0; r < 4; ++r) {
        const long row = rowb + r;
        const float iv = 1.0f / sums_ro[row];
        const long colb = bn + wc * 64 + fr;
#pragma unroll
        for (int nj = 0; nj < 4; ++nj)
          C[row * ldO + colb + nj * 16] = acc[mi][nj][r] * iv;
      }
    }
  }
}

// MT = Wk_bf * Wq_bf^T  (= M^T where M = Wq*Wk^T). grid(4,4,1).
__global__ __launch_bounds__(256, 3) void gemm_mt(
    const unsigned short* __restrict__ wkb, const unsigned short* __restrict__ wqb,
    unsigned short* __restrict__ MT)
{
  extern __shared__ char smem[];
  core128(wkb, wqb, MT, 512, 512, 512, 16,
          (long)blockIdx.x * 128, (long)blockIdx.y * 128, smem, 0,
          nullptr, nullptr, nullptr);
}

// Projections, grid(128,4,2): z=0: T = Xq*MT^T; z=1: Vt = Wvt*Xn^T [512x16384]
__global__ __launch_bounds__(256, 3) void gemm_proj(
    const unsigned short* __restrict__ Xq, const unsigned short* __restrict__ Xn,
    const unsigned short* __restrict__ MT, const unsigned short* __restrict__ Wvt,
    unsigned short* __restrict__ T, unsigned short* __restrict__ Vt)
{
  extern __shared__ char smem[];
  if (blockIdx.z == 0) {
    core128(Xq, MT, T, 512, 512, 512, 16,
            (long)blockIdx.x * 128, (long)blockIdx.y * 128, smem, 0,
            nullptr, nullptr, nullptr);
  } else {
    core128(Wvt, Xn, Vt, 512, 512, 16384, 16,
            (long)blockIdx.y * 128, (long)blockIdx.x * 128, smem, 0,
            nullptr, nullptr, nullptr);
  }
}

// Scores: E = masked?0:exp((T Xn^T)*scale) + rowsum atomics.
// grid(8,16,16): x=batch=XCD (T/Xn slices L2-resident), y=q panel, z=kv panel.
__global__ __launch_bounds__(256, 3) void gemm_scores(
    const unsigned short* __restrict__ T, const unsigned short* __restrict__ Xn,
    unsigned short* __restrict__ Eg, const unsigned long long* __restrict__ pm,
    float* __restrict__ sums)
{
  extern __shared__ char smem[];
  const long z = blockIdx.x;
  core128(T + z * 1048576, Xn + z * 1048576, Eg + z * 4194304,
          512, 512, 2048, 16,
          (long)blockIdx.y * 128, (long)blockIdx.z * 128, smem, 1,
          pm + z * 65536, sums + z * 2048, nullptr);
}

// PV: O = (E @ V) / rowsum, f32. grid(8,4,16): x=batch=XCD, y=d panel
// (FASTEST -> E panel L2-shared by 4 consecutive blocks, Vt slice resident),
// z=q panel.
__global__ __launch_bounds__(256, 3) void gemm_pv(
    const unsigned short* __restrict__ E, const unsigned short* __restrict__ Vt,
    const float* __restrict__ sums, float* __restrict__ O)
{
  extern __shared__ char smem[];
  const long z = blockIdx.x;                    // batch = XCD
  core128(E + z * 4194304, Vt + z * 2048, O + z * 1048576,
          2048, 16384, 512, 64,
          (long)blockIdx.z * 128, (long)blockIdx.y * 128, smem, 2,
          nullptr, nullptr, sums + z * 2048);
}

// ---------------------------------------------------------------------------
extern "C" void kernel_launch(void* const* d_in, const int* in_sizes, int n_in,
                              void* d_out, int out_size, void* d_ws, size_t ws_size,
                              hipStream_t stream) {
  const float* node  = (const float*)d_in[0];
  const float* query = (const float*)d_in[1];
  const unsigned char* mask = (const unsigned char*)d_in[2];
  const float* wq = (const float*)d_in[3];
  const float* wk = (const float*)d_in[4];
  const float* wv = (const float*)d_in[5];
  float* out = (float*)d_out;

  char* ws = (char*)d_ws;
  // ws: T @0 (16M) | Xn @16M (16M) | Vt @32M (16M) | E @48M..112M (64M)
  //     overlapped, dead before scores: Xq @48M; wqb/wkb/Wvt/MT @64M+
  //     sums @112M (64K) | pm @~113M (4M)
  unsigned short* T   = (unsigned short*)(ws);
  unsigned short* Xn  = (unsigned short*)(ws + 16777216);
  unsigned short* Vt  = (unsigned short*)(ws + 33554432);
  unsigned short* E   = (unsigned short*)(ws + 50331648);
  unsigned short* Xq  = (unsigned short*)(ws + 50331648);           // dead after T-proj
  unsigned short* wqb = (unsigned short*)(ws + 67108864);           // dead after MT
  unsigned short* wkb = (unsigned short*)(ws + 67633152);           // dead after MT
  unsigned short* Wvt = (unsigned short*)(ws + 68157440);           // dead after proj
  unsigned short* MT  = (unsigned short*)(ws + 68681728);           // dead after proj
  float* sums = (float*)(ws + 117440512);
  unsigned long long* pm = (unsigned long long*)(ws + 118489088);

  // One prep launch: mask pack + converts + weight copies + sums zeroing
  prep_all<<<21568, 256, 0, stream>>>(mask, pm, query, node, wq, wk, wv,
                                      Xq, Xn, wqb, wkb, Wvt, sums);

  // MT = Wk*Wq^T (512x512 tiny GEMM)
  gemm_mt<<<dim3(4, 4, 1), 256, 49152, stream>>>(wkb, wqb, MT);

  // Projections: T = Xq*MT^T and Vt = Wvt*Xn^T (K-projection eliminated by
  // associativity: S = Xq*(Wq Wk^T)*Xn^T)
  dim3 gp(128, 4, 2);
  gemm_proj<<<gp, 256, 49152, stream>>>(Xq, Xn, MT, Wvt, T, Vt);

  // Scores (+exp +mask +row sums): 2048 blocks
  dim3 gs(8, 16, 16);
  gemm_scores<<<gs, 256, 49152, stream>>>(T, Xn, E, pm, sums);

  // PV + normalize: 512 blocks, d-panel fastest per XCD
  dim3 gv(8, 4, 16);
  gemm_pv<<<gv, 256, 49152, stream>>>(E, Vt, sums, out);
}

// Round 19
// 189.884 us; speedup vs baseline: 1.3967x; 1.0340x over previous
//
#include <hip/hip_runtime.h>

typedef __attribute__((ext_vector_type(8))) short bf16x8;
typedef __attribute__((ext_vector_type(4))) float f32x4;

__device__ __forceinline__ unsigned short f2bf(float f) {
  unsigned int u = __builtin_bit_cast(unsigned int, f);
  u += 0x7fffu + ((u >> 16) & 1u);   // RNE
  return (unsigned short)(u >> 16);
}

#define GLD16(gp, lp) __builtin_amdgcn_global_load_lds( \
    (const __attribute__((address_space(1))) unsigned int*)(gp), \
    (__attribute__((address_space(3))) unsigned int*)(lp), 16, 0, 0)

// ---------------------------------------------------------------------------
// Merged prep: [0,2048) ballot mask-pack; [2048,18432) activation converts;
// [18432,21504) weight copies; tail sums zeroing.
__global__ __launch_bounds__(256) void prep_all(
    const unsigned char* __restrict__ m, unsigned long long* __restrict__ pm,
    const float* __restrict__ query, const float* __restrict__ node,
    const float* __restrict__ wq, const float* __restrict__ wk,
    const float* __restrict__ wv,
    unsigned short* __restrict__ Xq, unsigned short* __restrict__ Xn,
    unsigned short* __restrict__ wqb, unsigned short* __restrict__ wkb,
    unsigned short* __restrict__ wvt, float* __restrict__ sums)
{
  const int b = blockIdx.x;
  if (b < 2048) {
    // ---- mask pack, wave-cooperative ballot form ----
    // Mode probe: one u32/thread (int32 view). In int32 0/1 mode byte1 == 0
    // always; in bool mode byte1 hits a mask byte with p=0.3 per word
    // (P(miss over 256 words) = 0.7^256 ~ 0). Probe bytes are in-range for
    // both dtypes (b*16384+1024 <= 33.5MB).
    __shared__ int mode1;
    if (threadIdx.x == 0) mode1 = 0;
    __syncthreads();
    const unsigned int* m32 = (const unsigned int*)m;
    unsigned int pw = m32[(size_t)b * 4096 + threadIdx.x];
    if (pw & 0x0000ff00u) mode1 = 1;   // benign race
    __syncthreads();

    // Block covers pm words [b*256, b*256+256); wave w covers 64 of them.
    // Iteration it: lane l reads element g*64+l (coalesced), ballot -> word g.
    const int w = threadIdx.x >> 6;
    const int l = threadIdx.x & 63;
    const long gbase = (long)b * 256 + w * 64;
    unsigned long long myw = 0;
    if (mode1) {
      // 1-byte bool elements
      for (int it = 0; it < 64; ++it) {
        const unsigned char v = m[(gbase + it) * 64 + l];
        const unsigned long long bal = __ballot(v != 0);
        if (l == it) myw = bal;
      }
    } else {
      // 4-byte int elements: 256 B/wave per instr, streams 16KB contiguous
      for (int it = 0; it < 64; ++it) {
        const unsigned int v = m32[(gbase + it) * 64 + l];
        const unsigned long long bal = __ballot(v != 0);
        if (l == it) myw = bal;
      }
    }
    pm[gbase + l] = myw;               // coalesced 512 B/wave
  } else if (b < 18432) {
    int i = (b - 2048) * 256 + threadIdx.x;
    const float* src;
    unsigned short* dst;
    int j;
    if (i < 2097152) { src = query; dst = Xq; j = i; }
    else             { src = node;  dst = Xn; j = i - 2097152; }
    float4 v = ((const float4*)src)[j];
    ushort4 o;
    o.x = f2bf(v.x); o.y = f2bf(v.y); o.z = f2bf(v.z); o.w = f2bf(v.w);
    ((ushort4*)dst)[j] = o;
  } else if (b < 21504) {
    int idx = (b - 18432) * 256 + threadIdx.x;  // 0..786431
    int w = idx >> 18;
    int rem = idx & 262143;
    if (w == 0)      wqb[rem] = f2bf(wq[rem]);
    else if (w == 1) wkb[rem] = f2bf(wk[rem]);
    else {
      int n = rem >> 9, k = rem & 511;
      wvt[n * 512 + k] = f2bf(wv[k * 512 + n]);
    }
  } else {
    int idx = (b - 21504) * 256 + threadIdx.x;  // 0..16383
    sums[idx] = 0.0f;
  }
}

// ---------------------------------------------------------------------------
// Unified 128x128 core, 3 blocks/CU (r12/r14/r15-verified): BK=32, 4 waves,
// 3 bufs x 16KB = 48KB LDS. Stage t+2 during t; vmcnt ledger 8/4/0 (L=4).
// Swizzle: 16B-chunk ^= ((row>>1)&3) -> 2-way max (conflict-count 0, r14).
// mode 0: bf16 C. mode 1: scores epilogue (bitmask exp + rowsum atomics).
// mode 2: f32 C scaled by 1/sums[row].
__device__ __forceinline__ void core128(
    const unsigned short* __restrict__ Ab, const unsigned short* __restrict__ Bb,
    void* __restrict__ Cb, long ldA, long ldB, long ldO, int nk,
    long bm, long bn, char* smem, int mode,
    const unsigned long long* __restrict__ pmask, float* __restrict__ sumz,
    const float* __restrict__ sums_ro)
{
  const int tid = threadIdx.x;          // 0..255
  const int lane = tid & 63;
  const int wid = tid >> 6;
  const int wr = wid >> 1, wc = wid & 1;
  const int fr = lane & 15, fq = lane >> 4;

  const int srow = tid >> 2;            // 0..63
  const int sch = (tid & 3) ^ ((srow >> 1) & 3);   // pre-swizzled source chunk

  char* bufs[3] = { smem, smem + 16384, smem + 32768 };

#define STAGE_C(buf, kt) do { \
    const long k0_ = (long)(kt) << 5; \
    GLD16(Ab + (bm + srow) * ldA + k0_ + sch * 8,        (buf) + tid * 16); \
    GLD16(Ab + (bm + 64 + srow) * ldA + k0_ + sch * 8,   (buf) + 4096 + tid * 16); \
    GLD16(Bb + (bn + srow) * ldB + k0_ + sch * 8,        (buf) + 8192 + tid * 16); \
    GLD16(Bb + (bn + 64 + srow) * ldB + k0_ + sch * 8,   (buf) + 12288 + tid * 16); \
  } while (0)

  int aoff[4], boff[4];
#pragma unroll
  for (int i = 0; i < 4; ++i) {
    const int ra = wr * 64 + i * 16 + fr;
    aoff[i] = ra * 64 + (fq ^ ((ra >> 1) & 3)) * 16;
    const int rb = wc * 64 + i * 16 + fr;
    boff[i] = 8192 + rb * 64 + (fq ^ ((rb >> 1) & 3)) * 16;
  }

  f32x4 acc[4][4] = {};

  STAGE_C(bufs[0], 0);
  STAGE_C(bufs[1], 1);
  char* c0 = bufs[0]; char* c1 = bufs[1]; char* c2 = bufs[2];

  for (int t = 0; t < nk; ++t) {
    __builtin_amdgcn_sched_barrier(0);
    __builtin_amdgcn_s_barrier();       // B1: all reads of c2's old tile done
    if (t + 2 < nk) {
      STAGE_C(c2, t + 2);
      asm volatile("s_waitcnt vmcnt(8)" ::: "memory");   // tile t landed
    } else if (t + 2 == nk) {
      asm volatile("s_waitcnt vmcnt(4)" ::: "memory");
    } else {
      asm volatile("s_waitcnt vmcnt(0)" ::: "memory");
    }
    __builtin_amdgcn_s_barrier();       // B2: tile t visible to all waves
    __builtin_amdgcn_sched_barrier(0);

    bf16x8 a[4];
#pragma unroll
    for (int mi = 0; mi < 4; ++mi)
      a[mi] = *(const bf16x8*)(c0 + aoff[mi]);
    __builtin_amdgcn_s_setprio(1);
#pragma unroll
    for (int nj = 0; nj < 4; ++nj) {
      const bf16x8 b = *(const bf16x8*)(c0 + boff[nj]);
#pragma unroll
      for (int mi = 0; mi < 4; ++mi)
        acc[mi][nj] = __builtin_amdgcn_mfma_f32_16x16x32_bf16(a[mi], b, acc[mi][nj], 0, 0, 0);
    }
    __builtin_amdgcn_s_setprio(0);

    char* tmp = c0; c0 = c1; c1 = c2; c2 = tmp;
  }
#undef STAGE_C

  // Epilogue. C/D layout: col=lane&15, row=(lane>>4)*4+r  [m89-verified]
  const float SCALE = 0.04419417382415922f;  // 1/sqrt(512)
  if (mode == 0) {
    unsigned short* C = (unsigned short*)Cb;
#pragma unroll
    for (int mi = 0; mi < 4; ++mi)
#pragma unroll
      for (int nj = 0; nj < 4; ++nj) {
        const long row = bm + wr * 64 + mi * 16 + fq * 4;
        const long col = bn + wc * 64 + nj * 16 + fr;
#pragma unroll
        for (int r = 0; r < 4; ++r)
          C[(row + r) * ldO + col] = f2bf(acc[mi][nj][r]);
      }
  } else if (mode == 1) {
    unsigned short* C = (unsigned short*)Cb;
    const long wword = (bn >> 6) + wc;
#pragma unroll
    for (int mi = 0; mi < 4; ++mi) {
      const long rowb = bm + wr * 64 + mi * 16 + fq * 4;
#pragma unroll
      for (int r = 0; r < 4; ++r) {
        const long row = rowb + r;
        const unsigned long long w = pmask[row * 32 + wword];
        unsigned short* Crow = C + row * ldO + bn + wc * 64 + fr;
        float s = 0.f;
#pragma unroll
        for (int nj = 0; nj < 4; ++nj) {
          const int sh = nj * 16 + fr;
          float e = ((w >> sh) & 1ull) ? 0.0f : __expf(acc[mi][nj][r] * SCALE);
          s += e;
          Crow[nj * 16] = f2bf(e);
        }
        s += __shfl_xor(s, 1); s += __shfl_xor(s, 2);
        s += __shfl_xor(s, 4); s += __shfl_xor(s, 8);
        if (fr == 0) atomicAdd(&sumz[row], s);
      }
    }
  } else {
    float* C = (float*)Cb;
#pragma unroll
    for (int mi = 0; mi < 4; ++mi) {
      const long rowb = bm + wr * 64 + mi * 16 + fq * 4;
#pragma unroll
      for (int r = 0; r < 4; ++r) {
        const long row = rowb + r;
        const float iv = 1.0f / sums_ro[row];
        const long colb = bn + wc * 64 + fr;
#pragma unroll
        for (int nj = 0; nj < 4; ++nj)
          C[row * ldO + colb + nj * 16] = acc[mi][nj][r] * iv;
      }
    }
  }
}

// MT = Wk_bf * Wq_bf^T  (= M^T where M = Wq*Wk^T). grid(4,4,1).
__global__ __launch_bounds__(256, 3) void gemm_mt(
    const unsigned short* __restrict__ wkb, const unsigned short* __restrict__ wqb,
    unsigned short* __restrict__ MT)
{
  extern __shared__ char smem[];
  core128(wkb, wqb, MT, 512, 512, 512, 16,
          (long)blockIdx.x * 128, (long)blockIdx.y * 128, smem, 0,
          nullptr, nullptr, nullptr);
}

// Projections, grid(128,4,2): z=0: T = Xq*MT^T; z=1: Vt = Wvt*Xn^T [512x16384]
__global__ __launch_bounds__(256, 3) void gemm_proj(
    const unsigned short* __restrict__ Xq, const unsigned short* __restrict__ Xn,
    const unsigned short* __restrict__ MT, const unsigned short* __restrict__ Wvt,
    unsigned short* __restrict__ T, unsigned short* __restrict__ Vt)
{
  extern __shared__ char smem[];
  if (blockIdx.z == 0) {
    core128(Xq, MT, T, 512, 512, 512, 16,
            (long)blockIdx.x * 128, (long)blockIdx.y * 128, smem, 0,
            nullptr, nullptr, nullptr);
  } else {
    core128(Wvt, Xn, Vt, 512, 512, 16384, 16,
            (long)blockIdx.y * 128, (long)blockIdx.x * 128, smem, 0,
            nullptr, nullptr, nullptr);
  }
}

// Scores: E = masked?0:exp((T Xn^T)*scale) + rowsum atomics.
// grid(8,16,16): x=batch=XCD (T/Xn slices L2-resident), y=q panel, z=kv panel.
__global__ __launch_bounds__(256, 3) void gemm_scores(
    const unsigned short* __restrict__ T, const unsigned short* __restrict__ Xn,
    unsigned short* __restrict__ Eg, const unsigned long long* __restrict__ pm,
    float* __restrict__ sums)
{
  extern __shared__ char smem[];
  const long z = blockIdx.x;
  core128(T + z * 1048576, Xn + z * 1048576, Eg + z * 4194304,
          512, 512, 2048, 16,
          (long)blockIdx.y * 128, (long)blockIdx.z * 128, smem, 1,
          pm + z * 65536, sums + z * 2048, nullptr);
}

// PV: O = (E @ V) / rowsum, f32. grid(8,4,16): x=batch=XCD, y=d panel
// (FASTEST -> E panel L2-shared by 4 consecutive blocks, Vt slice resident),
// z=q panel.
__global__ __launch_bounds__(256, 3) void gemm_pv(
    const unsigned short* __restrict__ E, const unsigned short* __restrict__ Vt,
    const float* __restrict__ sums, float* __restrict__ O)
{
  extern __shared__ char smem[];
  const long z = blockIdx.x;                    // batch = XCD
  core128(E + z * 4194304, Vt + z * 2048, O + z * 1048576,
          2048, 16384, 512, 64,
          (long)blockIdx.z * 128, (long)blockIdx.y * 128, smem, 2,
          nullptr, nullptr, sums + z * 2048);
}

// ---------------------------------------------------------------------------
extern "C" void kernel_launch(void* const* d_in, const int* in_sizes, int n_in,
                              void* d_out, int out_size, void* d_ws, size_t ws_size,
                              hipStream_t stream) {
  const float* node  = (const float*)d_in[0];
  const float* query = (const float*)d_in[1];
  const unsigned char* mask = (const unsigned char*)d_in[2];
  const float* wq = (const float*)d_in[3];
  const float* wk = (const float*)d_in[4];
  const float* wv = (const float*)d_in[5];
  float* out = (float*)d_out;

  char* ws = (char*)d_ws;
  // ws: T @0 (16M) | Xn @16M (16M) | Vt @32M (16M) | E @48M..112M (64M)
  //     overlapped, dead before scores: Xq @48M; wqb/wkb/Wvt/MT @64M+
  //     sums @112M (64K) | pm @~113M (4M)
  unsigned short* T   = (unsigned short*)(ws);
  unsigned short* Xn  = (unsigned short*)(ws + 16777216);
  unsigned short* Vt  = (unsigned short*)(ws + 33554432);
  unsigned short* E   = (unsigned short*)(ws + 50331648);
  unsigned short* Xq  = (unsigned short*)(ws + 50331648);           // dead after T-proj
  unsigned short* wqb = (unsigned short*)(ws + 67108864);           // dead after MT
  unsigned short* wkb = (unsigned short*)(ws + 67633152);           // dead after MT
  unsigned short* Wvt = (unsigned short*)(ws + 68157440);           // dead after proj
  unsigned short* MT  = (unsigned short*)(ws + 68681728);           // dead after proj
  float* sums = (float*)(ws + 117440512);
  unsigned long long* pm = (unsigned long long*)(ws + 118489088);

  // One prep launch: mask pack + converts + weight copies + sums zeroing
  prep_all<<<21568, 256, 0, stream>>>(mask, pm, query, node, wq, wk, wv,
                                      Xq, Xn, wqb, wkb, Wvt, sums);

  // MT = Wk*Wq^T (512x512 tiny GEMM)
  gemm_mt<<<dim3(4, 4, 1), 256, 49152, stream>>>(wkb, wqb, MT);

  // Projections: T = Xq*MT^T and Vt = Wvt*Xn^T (K-projection eliminated by
  // associativity: S = Xq*(Wq Wk^T)*Xn^T)
  dim3 gp(128, 4, 2);
  gemm_proj<<<gp, 256, 49152, stream>>>(Xq, Xn, MT, Wvt, T, Vt);

  // Scores (+exp +mask +row sums): 2048 blocks
  dim3 gs(8, 16, 16);
  gemm_scores<<<gs, 256, 49152, stream>>>(T, Xn, E, pm, sums);

  // PV + normalize: 512 blocks, d-panel fastest per XCD
  dim3 gv(8, 4, 16);
  gemm_pv<<<gv, 256, 49152, stream>>>(E, Vt, sums, out);
}